// Round 1
// baseline (92.091 us; speedup 1.0000x reference)
//
#include <hip/hip_runtime.h>

// SimplifiedMambaBlock analysis:
//   The scan's state update is h = A_t * h with h0 = 0 and NO additive input
//   term, so h stays exactly 0.0f for every timestep. Hence ssm_out == 0,
//   y = ssm_out * z == 0, and out = einsum(0, out_proj_w) + residual == x
//   bit-exactly in fp32. The whole norm/proj/silu/scan pipeline is dead code
//   w.r.t. the output. Optimal kernel = D2D copy of x into d_out.
//   Traffic: 8*2048*512 * 4 B = 32 MiB each way -> ~10 us at ~6.3 TB/s.

extern "C" void kernel_launch(void* const* d_in, const int* in_sizes, int n_in,
                              void* d_out, int out_size, void* d_ws, size_t ws_size,
                              hipStream_t stream) {
    const void* x = d_in[0];  // (8, 2048, 512) float32 == out shape/dtype
    hipMemcpyAsync(d_out, x, (size_t)out_size * sizeof(float),
                   hipMemcpyDeviceToDevice, stream);
}